// Round 11
// baseline (103.668 us; speedup 1.0000x reference)
//
#include <hip/hip_runtime.h>
#include <cmath>

// x,y: (16,3,512,512) f32. Fused separable-Gaussian SSIM, scalar mean output.
// 128-thread blocks, 2-row rounds: v-conv streams 12 input rows (float4/lane,
// products recomputed), hands off via a 21KB bank-swizzled LDS buffer; h-conv
// 8 cols/lane (2 waves <-> 2 rows). High residency (~7 blocks/CU) hides
// latency; cheap 2-wave barriers.
constexpr int IMG_H = 512;
constexpr int IMG_W = 512;
constexpr int PLANES = 48;
constexpr int R_OUT = 8;                 // output rows per block (4 rounds of 2)
constexpr int BANDS = IMG_H / R_OUT;     // 64
constexpr int PSTR = 528;                // field-row dwords; col c at p = c+8
constexpr long long TOTAL_PIX = (long long)PLANES * IMG_H * IMG_W;

struct GWin { float g[11]; };

// XOR bank swizzle on within-field-row dword offset. Flips bits 2..4 from
// bits 5..7: 4-aligned offsets stay 4-aligned, b128 groups stay contiguous;
// write (float4 at swzd(4t+8)) and read (float4 at 4*(blk^((blk>>3)&7)))
// address the same physical slots.
__device__ __forceinline__ int swzd(int p) { return p ^ (((p >> 5) & 7) << 2); }

template<bool CHK>
__device__ __forceinline__ float4 ld4(const float* __restrict__ base, int gr, int c0) {
    if (CHK && (unsigned)gr >= (unsigned)IMG_H) return make_float4(0.f, 0.f, 0.f, 0.f);
    return *(const float4*)(base + (size_t)gr * IMG_W + c0);
}

// horizontal 11-tap conv + SSIM over one LDS row (5 fields), 8 cols per lane
__device__ __forceinline__ float hpass8(const float (* __restrict__ fr)[PSTR],
                                        int l, const GWin& win) {
    int pb[6];
#pragma unroll
    for (int B = 0; B < 6; ++B) {
        const int blk = 2 * l + B;
        pb[B] = blk ^ ((blk >> 3) & 7);
    }
    float m[5][8];
#pragma unroll
    for (int f = 0; f < 5; ++f) {
        float w24[24];
#pragma unroll
        for (int B = 0; B < 6; ++B) {
            const float4 v = *(const float4*)&fr[f][4 * pb[B]];
            w24[4 * B + 0] = v.x;  w24[4 * B + 1] = v.y;
            w24[4 * B + 2] = v.z;  w24[4 * B + 3] = v.w;
        }
        // output col c = 8l+j; window floats p = c+3..c+13 -> w24[j+3+k]
#pragma unroll
        for (int j = 0; j < 8; ++j) {
            float s = 0.f;
#pragma unroll
            for (int k = 0; k < 11; ++k) s += win.g[k] * w24[j + 3 + k];
            m[f][j] = s;
        }
    }
    float ls = 0.f;
#pragma unroll
    for (int u = 0; u < 8; ++u) {
        const float mx  = m[0][u], my  = m[1][u];
        const float mxx = m[2][u], myy = m[3][u], mxy = m[4][u];
        const float mu_x_sq = mx * mx;
        const float mu_y_sq = my * my;
        const float mu_xy   = mx * my;
        const float sig_x  = mxx - mu_x_sq;
        const float sig_y  = myy - mu_y_sq;
        const float sig_xy = mxy - mu_xy;
        const float C1 = 0.01f * 0.01f;
        const float C2 = 0.03f * 0.03f;
        const float n = (2.f * mu_xy + C1) * (2.f * sig_xy + C2);
        const float d = (mu_x_sq + mu_y_sq + C1) * (sig_x + sig_y + C2);
        ls += n * __builtin_amdgcn_rcpf(d + 1e-8f);   // ~1 ulp; mean-safe
    }
    return ls;
}

template<bool CHK>
__device__ __forceinline__ float rounds_body(const float* __restrict__ xp,
                                             const float* __restrict__ yp,
                                             int r0, int c0, int tid,
                                             float (&hbuf)[2][5][PSTR],
                                             const GWin& win)
{
    const int pws = swzd(4 * tid + 8);   // v-write physical offset (b128-consistent)
    const int row = tid >> 6, l = tid & 63;
    float lsum = 0.f;

#pragma unroll 1
    for (int rr = 0; rr < 4; ++rr) {
        const int rbase = r0 + 2 * rr;

        // ---- vertical 11-tap conv of {x,y,xx,yy,xy} for rows rbase, rbase+1 ----
        float4 acc[2][5];
#pragma unroll
        for (int j = 0; j < 2; ++j)
#pragma unroll
            for (int f = 0; f < 5; ++f) acc[j][f] = make_float4(0.f, 0.f, 0.f, 0.f);

#pragma unroll
        for (int i = 0; i < 12; ++i) {
            const float4 xv = ld4<CHK>(xp, rbase - 5 + i, c0);
            const float4 yv = ld4<CHK>(yp, rbase - 5 + i, c0);
            const float4 pxx = make_float4(xv.x * xv.x, xv.y * xv.y, xv.z * xv.z, xv.w * xv.w);
            const float4 pyy = make_float4(yv.x * yv.x, yv.y * yv.y, yv.z * yv.z, yv.w * yv.w);
            const float4 pxy = make_float4(xv.x * yv.x, xv.y * yv.y, xv.z * yv.z, xv.w * yv.w);
#pragma unroll
            for (int j = 0; j < 2; ++j) {
                const int t = i - j;              // compile-time
                if (t >= 0 && t <= 10) {
                    const float g = win.g[t];
                    acc[j][0].x += g * xv.x;  acc[j][0].y += g * xv.y;
                    acc[j][0].z += g * xv.z;  acc[j][0].w += g * xv.w;
                    acc[j][1].x += g * yv.x;  acc[j][1].y += g * yv.y;
                    acc[j][1].z += g * yv.z;  acc[j][1].w += g * yv.w;
                    acc[j][2].x += g * pxx.x; acc[j][2].y += g * pxx.y;
                    acc[j][2].z += g * pxx.z; acc[j][2].w += g * pxx.w;
                    acc[j][3].x += g * pyy.x; acc[j][3].y += g * pyy.y;
                    acc[j][3].z += g * pyy.z; acc[j][3].w += g * pyy.w;
                    acc[j][4].x += g * pxy.x; acc[j][4].y += g * pxy.y;
                    acc[j][4].z += g * pxy.z; acc[j][4].w += g * pxy.w;
                }
            }
        }

#pragma unroll
        for (int j = 0; j < 2; ++j)
#pragma unroll
            for (int f = 0; f < 5; ++f)
                *(float4*)&hbuf[j][f][pws] = acc[j][f];

        __syncthreads();

        lsum += hpass8(hbuf[row], l, win);

        __syncthreads();   // protect hbuf before next round's writes
    }
    return lsum;
}

__global__ __launch_bounds__(128)
void ssim_rr_kernel(const float* __restrict__ x,
                    const float* __restrict__ y,
                    double* __restrict__ accum,
                    GWin win)
{
    __shared__ __align__(16) float hbuf[2][5][PSTR];   // 21.1 KB
    __shared__ float wsum[2];

    const int tid   = threadIdx.x;
    const int band  = blockIdx.x & (BANDS - 1);
    const int plane = blockIdx.x >> 6;
    const int r0    = band * R_OUT;
    const int c0    = tid * 4;

    const float* __restrict__ xp = x + (size_t)plane * (IMG_H * IMG_W);
    const float* __restrict__ yp = y + (size_t)plane * (IMG_H * IMG_W);

    // zero halo cols: p in [0,8) and [520,528), 2 rows x 5 fields (swizzled slots)
    for (int i = tid; i < 160; i += 128) {
        int rf = i >> 4, w = i & 15;
        int p  = (w < 8) ? w : (512 + w);       // 0..7, 520..527
        (&hbuf[0][0][0])[rf * PSTR + swzd(p)] = 0.f;
    }
    // (ordered before first h-read by the first in-round __syncthreads)

    float lsum;
    if (band >= 1 && band <= BANDS - 2)
        lsum = rounds_body<false>(xp, yp, r0, c0, tid, hbuf, win);
    else
        lsum = rounds_body<true>(xp, yp, r0, c0, tid, hbuf, win);

    // block reduction (2 waves)
#pragma unroll
    for (int off = 32; off; off >>= 1) lsum += __shfl_down(lsum, off);
    if ((tid & 63) == 0) wsum[tid >> 6] = lsum;
    __syncthreads();
    if (tid == 0)
        atomicAdd(accum, (double)(wsum[0] + wsum[1]));
}

__global__ void ssim_finalize_kernel(const double* __restrict__ accum,
                                     float* __restrict__ out)
{
    out[0] = (float)(accum[0] / (double)TOTAL_PIX);
}

extern "C" void kernel_launch(void* const* d_in, const int* in_sizes, int n_in,
                              void* d_out, int out_size, void* d_ws, size_t ws_size,
                              hipStream_t stream) {
    const float* x = (const float*)d_in[0];
    const float* y = (const float*)d_in[1];
    float* out = (float*)d_out;
    double* accum = (double*)d_ws;

    GWin win;
    {
        double g[11], s = 0.0;
        for (int i = 0; i < 11; ++i) {
            double d = (double)i - 5.0;
            g[i] = std::exp(-(d * d) / (2.0 * 1.5 * 1.5));
            s += g[i];
        }
        for (int i = 0; i < 11; ++i) win.g[i] = (float)(g[i] / s);
    }

    hipMemsetAsync(d_ws, 0, sizeof(double), stream);

    const int nblocks = PLANES * BANDS;  // 3072
    ssim_rr_kernel<<<nblocks, 128, 0, stream>>>(x, y, accum, win);
    ssim_finalize_kernel<<<1, 1, 0, stream>>>(accum, out);
}